// Round 5
// baseline (3784.156 us; speedup 1.0000x reference)
//
#include <hip/hip_runtime.h>
#include <math.h>

// ============================================================================
// RSSM forward on MI355X.
// Round 8: 5 -> 4 barriers + cheaper barrier + hoisted coherent loads.
// R7 post-mortem: step = 11.3us = 5 x ~2.26us barrier segments (MfmaUtil 2.3%,
// VALUBusy 5.3% -> pure latency chain of store-drain / counter-RMW / poll /
// coherent-read round trips to the coherence point).
// Changes:
//  (1) Replicate the posterior heads: after the M2 barrier every member reads
//      full m2 anyway; computing full mu/var (head weights streamed from wt,
//      L2-resident) + full sample makes s block-local (LDS sF) -> gin needs no
//      exchange -> S barrier and XS buffer GONE. Same MFMA tile order ->
//      bit-identical results; each member stores only its own 16 out cols.
//  (2) Distributed flag barrier: member j posts flag[ph][g][j]=epoch (plain
//      relaxed store, no RMW); lanes 0..7 poll all 8 flags in one vector load.
//  (3) Hoist stable coherent loads across barriers (GRU's ah before G-flag,
//      po1h's pv before H-flag) so their latency hides under the barrier wait.
//  (4) post_pass: 64 rows/block (1016 blocks) -> 4x less weight re-read.
// ============================================================================

using v8s   = __attribute__((ext_vector_type(8))) short;
using f32x4 = __attribute__((ext_vector_type(4))) float;
typedef unsigned long long u64;

#define BN   512
#define TN   128
#define LATN 128

#define AB_S 264   // 256-col LDS activation stride (shorts) - post_pass/big_gemm

// pre-shuffled weight tile bases (1 tile = 16n x 32k bf16 = 1KB = 512 shorts)
#define OBS1_T 0
#define OBS2_T 256
#define PO1O_T 384
#define PO1H_T 512
#define GINS_T 640
#define IH_T   704
#define HH_T   1088
#define PR1_T  1472
#define PR2_T  1600
#define PRM_T  1728
#define PRV_T  1792
#define PO2_T  1856
#define POM_T  1984
#define POV_T  2048
#define TOT_TILES 2112

#define B1_BYTES 33554432UL          // 65536 x 256 bf16
#define KL_OFF   8388608UL           // states elements (512*128*128)

// local (LDS) tile bases for the rnn weight slices
#define GIN_L 0     // 8 tiles
#define IH_L  8     // 48
#define HH_L  56    // 48
#define P1_L  104   // 16
#define P2_L  120   // 16
#define NLT   136

__device__ __forceinline__ unsigned short f2bf(float f){
  union { float f; unsigned u; } v; v.f = f;
  unsigned u = v.u + 0x7fffu + ((v.u >> 16) & 1u);   // RNE
  return (unsigned short)(u >> 16);
}
__device__ __forceinline__ float bf2f(unsigned short s){
  union { unsigned u; float f; } v; v.u = ((unsigned)s) << 16; return v.f;
}
__device__ __forceinline__ float sigm(float x){ return 1.f / (1.f + __expf(-x)); }
__device__ __forceinline__ float tanhx(float x){ return 1.f - 2.f/(__expf(2.f*x) + 1.f); }

#define MFMA16(a,b,c) __builtin_amdgcn_mfma_f32_16x16x32_bf16((a),(b),(c),0,0,0)
#define LDB(tIdx) (*(const v8s*)(wt + ((size_t)(tIdx))*512 + lane*8))

// device-coherent exchange primitives (complete at the coherence point; no
// wbl2/inv cache maintenance)
__device__ __forceinline__ v8s ldx16(const unsigned short* p){
  union { u64 u[2]; v8s v; } x;
  x.u[0] = __hip_atomic_load((u64*)p,     __ATOMIC_RELAXED, __HIP_MEMORY_SCOPE_AGENT);
  x.u[1] = __hip_atomic_load((u64*)p + 1, __ATOMIC_RELAXED, __HIP_MEMORY_SCOPE_AGENT);
  return x.v;
}
__device__ __forceinline__ void stxs(unsigned short* p, unsigned short v){
  __hip_atomic_store(p, v, __ATOMIC_RELAXED, __HIP_MEMORY_SCOPE_AGENT);
}

// ---------------------------------------------------------------------------
// Weight shuffle: f32 (N,K) row-major -> bf16 fragment-linear tiles.
// ---------------------------------------------------------------------------
struct ShufArgs {
  const float* src[14];
  int stride[14], coloff[14], ktiles[14], tbase[14], tcnt[14];
};

__global__ __launch_bounds__(64) void shuffle_w(ShufArgs sa, unsigned short* __restrict__ wt)
{
  int tile = blockIdx.x;
  int s = 0;
  while (tile >= sa.tbase[s] + sa.tcnt[s]) s++;
  int lt = tile - sa.tbase[s];
  int kt = lt % sa.ktiles[s];
  int nt = lt / sa.ktiles[s];
  int l  = threadIdx.x;
  int n  = nt*16 + (l & 15);
  int k  = sa.coloff[s] + kt*32 + (l >> 4)*8;
  const float* sp = sa.src[s] + (size_t)n * sa.stride[s] + k;
  unsigned short* dp = wt + (size_t)tile*512 + (size_t)l*8;
  #pragma unroll
  for (int j = 0; j < 8; j++) dp[j] = f2bf(sp[j]);
}

// ---------------------------------------------------------------------------
// Parallel GEMM for obs MLP / po1_o precompute.
// ---------------------------------------------------------------------------
__global__ __launch_bounds__(256) void big_gemm(
    const void* __restrict__ Ain, int aIsF32, int K,
    const unsigned short* __restrict__ wt, int tbase,
    const float* __restrict__ bias, int doRelu,
    unsigned short* __restrict__ outB)
{
  __shared__ unsigned short AL[64*AB_S];
  int tid = threadIdx.x, lane = tid & 63, wv = tid >> 6;
  int q = lane >> 4, c16 = lane & 15;
  size_t row0 = (size_t)blockIdx.x * 64;

  f32x4 acc[16];
  #pragma unroll
  for (int nt = 0; nt < 16; nt++) acc[nt] = (f32x4){0.f,0.f,0.f,0.f};

  int nchunk = K >> 8;
  int ktT    = K >> 5;
  for (int cc = 0; cc < nchunk; cc++){
    int r = tid >> 2, c0 = (tid & 3) * 64;
    if (aIsF32){
      const float* A = (const float*)Ain + (row0 + r) * (size_t)K + (size_t)cc*256 + c0;
      #pragma unroll
      for (int ii = 0; ii < 16; ii++){
        float4 x = ((const float4*)A)[ii];
        ushort4 o;
        o.x = f2bf(x.x); o.y = f2bf(x.y); o.z = f2bf(x.z); o.w = f2bf(x.w);
        *(ushort4*)&AL[r*AB_S + c0 + ii*4] = o;
      }
    } else {
      const unsigned short* A = (const unsigned short*)Ain + (row0 + r)*256 + c0;
      #pragma unroll
      for (int ii = 0; ii < 8; ii++)
        *(v8s*)&AL[r*AB_S + c0 + ii*8] = *(const v8s*)(A + ii*8);
    }
    __syncthreads();
    const unsigned short* myA = &AL[wv*16*AB_S];
    #pragma unroll
    for (int kt = 0; kt < 8; kt++){
      v8s af = *(const v8s*)&myA[c16*AB_S + kt*32 + q*8];
      #pragma unroll
      for (int nt = 0; nt < 16; nt++){
        v8s bf = *(const v8s*)(wt + ((size_t)(tbase + nt*ktT + cc*8 + kt))*512 + lane*8);
        acc[nt] = MFMA16(af, bf, acc[nt]);
      }
    }
    __syncthreads();
  }
  #pragma unroll
  for (int nt = 0; nt < 16; nt++){
    int col = nt*16 + c16;
    float b = bias[col];
    #pragma unroll
    for (int i = 0; i < 4; i++){
      float v = acc[nt][i] + b;
      if (doRelu) v = fmaxf(v, 0.f);
      outB[(row0 + wv*16 + q*4 + i)*256 + col] = f2bf(v);
    }
  }
}

// ---------------------------------------------------------------------------
// post_pass helpers (16 rows x 256 cols, 16 waves; wave wv owns nt = wv).
// ---------------------------------------------------------------------------
__device__ __forceinline__ void stage256(
    const unsigned short* __restrict__ inA,
    const unsigned short* __restrict__ wt, int tbase,
    const float* __restrict__ bias,
    unsigned short* __restrict__ outA, int lane, int wv)
{
  int q = lane >> 4, c16 = lane & 15;
  v8s wf[8];
  #pragma unroll
  for (int kt = 0; kt < 8; kt++) wf[kt] = LDB(tbase + wv*8 + kt);
  v8s af[8];
  #pragma unroll
  for (int kt = 0; kt < 8; kt++) af[kt] = *(const v8s*)&inA[c16*AB_S + kt*32 + q*8];
  f32x4 acc = (f32x4){0.f,0.f,0.f,0.f};
  #pragma unroll
  for (int kt = 0; kt < 8; kt++) acc = MFMA16(af[kt], wf[kt], acc);
  int col = wv*16 + c16;
  float b = bias[col];
  #pragma unroll
  for (int i = 0; i < 4; i++)
    outA[(q*4 + i)*AB_S + col] = f2bf(fmaxf(acc[i] + b, 0.f));
}

__device__ __forceinline__ void pheads(
    const unsigned short* __restrict__ X2,
    const unsigned short* __restrict__ wt, int tM, int tV,
    const float* __restrict__ bM, const float* __restrict__ bV,
    float* __restrict__ muF, float* __restrict__ varF, int lane, int wv)
{
  int q = lane >> 4, c16 = lane & 15;
  int mtx = wv >> 3, nt = wv & 7;
  int tb  = mtx ? tV : tM;
  v8s wf[8];
  #pragma unroll
  for (int kt = 0; kt < 8; kt++) wf[kt] = LDB(tb + nt*8 + kt);
  v8s af[8];
  #pragma unroll
  for (int kt = 0; kt < 8; kt++) af[kt] = *(const v8s*)&X2[c16*AB_S + kt*32 + q*8];
  f32x4 acc = (f32x4){0.f,0.f,0.f,0.f};
  #pragma unroll
  for (int kt = 0; kt < 8; kt++) acc = MFMA16(af[kt], wf[kt], acc);
  int col = nt*16 + c16;
  float b = mtx ? bV[col] : bM[col];
  float* dst = mtx ? varF : muF;
  #pragma unroll
  for (int i = 0; i < 4; i++){
    float v = acc[i] + b;
    if (mtx) v = __expf(v) + 0.01f;
    dst[(q*4 + i)*LATN + col] = v;
  }
}

__device__ __forceinline__ void pstage_add(
    const unsigned short* __restrict__ inA,
    const unsigned short* __restrict__ wt, int tbase,
    const unsigned short* __restrict__ Pbuf, int row0,
    unsigned short* __restrict__ outA, int lane, int wv)
{
  int q = lane >> 4, c16 = lane & 15;
  v8s wf[8];
  #pragma unroll
  for (int kt = 0; kt < 8; kt++) wf[kt] = LDB(tbase + wv*8 + kt);
  v8s af[8];
  #pragma unroll
  for (int kt = 0; kt < 8; kt++) af[kt] = *(const v8s*)&inA[c16*AB_S + kt*32 + q*8];
  int col = wv*16 + c16;
  unsigned short pv[4];
  #pragma unroll
  for (int i = 0; i < 4; i++){
    int grow = row0 + q*4 + i;          // = b*127 + t
    int prow = grow + grow/127 + 1;     // = b*128 + (t+1)
    pv[i] = __builtin_nontemporal_load(&Pbuf[(size_t)prow*256 + col]);
  }
  f32x4 acc = (f32x4){0.f,0.f,0.f,0.f};
  #pragma unroll
  for (int kt = 0; kt < 8; kt++) acc = MFMA16(af[kt], wf[kt], acc);
  #pragma unroll
  for (int i = 0; i < 4; i++){
    float v = acc[i] + bf2f(pv[i]);
    outA[(q*4 + i)*AB_S + col] = f2bf(fmaxf(v, 0.f));
  }
}

// ---------------------------------------------------------------------------
// Distributed-flag group barrier. Member j posts flag[j]=ep (plain relaxed
// agent store, fire-and-forget); lanes 0..7 poll all 8 flags with one vector
// load per iteration. __syncthreads' vmcnt(0) drain puts the exchange stores
// at the coherence point before the flag store issues.
// ---------------------------------------------------------------------------
__device__ __forceinline__ void gsync(unsigned* f8, int j, unsigned ep, int tid)
{
  __syncthreads();
  if (tid == 0)
    __hip_atomic_store(f8 + j, ep, __ATOMIC_RELAXED, __HIP_MEMORY_SCOPE_AGENT);
  if (tid < 8){
    while (__hip_atomic_load(f8 + tid, __ATOMIC_RELAXED, __HIP_MEMORY_SCOPE_AGENT) < ep)
      __builtin_amdgcn_s_sleep(1);
  }
  __syncthreads();
}

// ---------------------------------------------------------------------------
// Distributed recurrence. Grid 256 = 32 groups x 8 members; group g handles
// batch rows g*16..g*16+15; member j owns output cols [32j,32j+32) of the
// 256-wide stages. Heads + sample are fully replicated per member (s is
// block-local in sF). 128 threads = 2 waves.
// ---------------------------------------------------------------------------
struct RnnArgs {
  const unsigned short *wt, *Pbuf;
  const float *actions, *noise, *w_gin, *b_gin, *b_ih, *b_hh, *b_po2, *b_pom, *b_pov;
  unsigned short *Hb, *XG, *XH, *XM1, *XM2;
  unsigned *flg;
  float *out;
};

__global__ __launch_bounds__(128, 1) void rssm_rnn(RnnArgs A)
{
  __shared__ unsigned short Lw[NLT*512];     // 139264 B weight slices
  __shared__ float LwaA[256];                // w_gin action part [32 cols][8]
  __shared__ float Lbg[32], Lbih[96], Lbhh[96], Lbp2[32];
  __shared__ float Lbm[128], Lbv[128];       // full head biases (replicated heads)
  __shared__ float varF[16*128];             // full var (f32), written by wave1
  __shared__ unsigned short sF[16*136];      // full s (bf16), block-local
  __shared__ float aF[128];

  int tid = threadIdx.x, lane = tid & 63, wv = tid >> 6;
  int q = lane >> 4, c16 = lane & 15;
  int g = blockIdx.x & 31, j = blockIdx.x >> 5;
  int b0 = g * 16;
  int lc = wv*16 + c16;          // local col in the 32-wide slice
  int gc = 32*j + lc;            // global col

  // ---- pin weight slices in LDS ----
  for (int u = tid; u < NLT*64; u += 128){
    int lt = u >> 6, ch = u & 63;
    int gt;
    if (lt < 8){
      int w = lt >> 2, kt = lt & 3;
      gt = GINS_T + (2*j + w)*4 + kt;
    } else if (lt < 56){
      int u2 = lt - 8;
      gt = IH_T + ((u2 >> 4)*16 + 2*j + ((u2 >> 3) & 1))*8 + (u2 & 7);
    } else if (lt < 104){
      int u2 = lt - 56;
      gt = HH_T + ((u2 >> 4)*16 + 2*j + ((u2 >> 3) & 1))*8 + (u2 & 7);
    } else if (lt < 120){
      int u2 = lt - 104;
      gt = PO1H_T + (2*j + (u2 >> 3))*8 + (u2 & 7);
    } else {
      int u2 = lt - 120;
      gt = PO2_T + (2*j + (u2 >> 3))*8 + (u2 & 7);
    }
    *(v8s*)&Lw[lt*512 + ch*8] = *(const v8s*)(A.wt + (size_t)gt*512 + ch*8);
  }
  for (int u = tid; u < 256; u += 128)
    LwaA[u] = A.w_gin[(size_t)(32*j + (u >> 3))*136 + 128 + (u & 7)];
  if (tid < 32){ Lbg[tid] = A.b_gin[32*j + tid]; Lbp2[tid] = A.b_po2[32*j + tid]; }
  if (tid >= 32 && tid < 128){
    int u = tid - 32;
    if (u < 96){
      Lbih[u] = A.b_ih[(u >> 5)*256 + 32*j + (u & 31)];
      Lbhh[u] = A.b_hh[(u >> 5)*256 + 32*j + (u & 31)];
    }
  }
  Lbm[tid] = A.b_pom[tid];
  Lbv[tid] = A.b_pov[tid];

  float hFr[4] = {0.f, 0.f, 0.f, 0.f};   // f32 h carry, rows q*4+i, col gc
  __syncthreads();

  unsigned* FG  = A.flg + (0*32 + g)*8;
  unsigned* FH  = A.flg + (1*32 + g)*8;
  unsigned* FM1 = A.flg + (2*32 + g)*8;
  unsigned* FM2 = A.flg + (3*32 + g)*8;
  const size_t sl = (size_t)(g*8);   // slice index base for this group

  for (int t = -1; t < TN-1; t++){
    if (t >= 0){
      int p = t & 1;
      // ---- gin: g = relu(s @ WginS^T + a @ WginA^T + b_gin), s from sF ----
      {
        v8s af4[4], wf[4];
        #pragma unroll
        for (int kt = 0; kt < 4; kt++)
          af4[kt] = *(const v8s*)&sF[c16*136 + kt*32 + q*8];
        #pragma unroll
        for (int kt = 0; kt < 4; kt++)
          wf[kt] = *(const v8s*)&Lw[(GIN_L + wv*4 + kt)*512 + lane*8];
        f32x4 acc = (f32x4){0.f,0.f,0.f,0.f};
        #pragma unroll
        for (int kt = 0; kt < 4; kt++) acc = MFMA16(af4[kt], wf[kt], acc);
        float bg = Lbg[lc];
        #pragma unroll
        for (int i = 0; i < 4; i++){
          int r = q*4 + i;
          float v = acc[i] + bg;
          #pragma unroll
          for (int m = 0; m < 8; m++) v += aF[r*8 + m]*LwaA[lc*8 + m];
          stxs(&A.XG[((sl + j)*16 + r)*32 + lc], f2bf(fmaxf(v, 0.f)));
        }
      }
      // hoist: ah from XH[p] (stable since last step's H barrier)
      v8s ah[8];
      #pragma unroll
      for (int kt = 0; kt < 8; kt++)
        ah[kt] = ldx16(A.XH + (((size_t)p*256 + sl + kt)*16 + c16)*32 + q*8);
      gsync(FG, j, (unsigned)(t+1), tid);
      // ---- GRU ----
      {
        v8s ag[8];
        #pragma unroll
        for (int kt = 0; kt < 8; kt++)
          ag[kt] = ldx16(A.XG + ((sl + kt)*16 + c16)*32 + q*8);
        f32x4 accI[3];
        #pragma unroll
        for (int x = 0; x < 3; x++){
          v8s wf[8];
          #pragma unroll
          for (int kt = 0; kt < 8; kt++)
            wf[kt] = *(const v8s*)&Lw[(IH_L + (x*2 + wv)*8 + kt)*512 + lane*8];
          accI[x] = (f32x4){0.f,0.f,0.f,0.f};
          #pragma unroll
          for (int kt = 0; kt < 8; kt++) accI[x] = MFMA16(ag[kt], wf[kt], accI[x]);
        }
        float rg[4], zg[4];
        {
          v8s wf[8];
          #pragma unroll
          for (int kt = 0; kt < 8; kt++)
            wf[kt] = *(const v8s*)&Lw[(HH_L + (0*2 + wv)*8 + kt)*512 + lane*8];
          f32x4 a = (f32x4){0.f,0.f,0.f,0.f};
          #pragma unroll
          for (int kt = 0; kt < 8; kt++) a = MFMA16(ah[kt], wf[kt], a);
          float bir = Lbih[lc], bhr = Lbhh[lc];
          #pragma unroll
          for (int i = 0; i < 4; i++) rg[i] = sigm(accI[0][i] + bir + a[i] + bhr);
        }
        {
          v8s wf[8];
          #pragma unroll
          for (int kt = 0; kt < 8; kt++)
            wf[kt] = *(const v8s*)&Lw[(HH_L + (1*2 + wv)*8 + kt)*512 + lane*8];
          f32x4 a = (f32x4){0.f,0.f,0.f,0.f};
          #pragma unroll
          for (int kt = 0; kt < 8; kt++) a = MFMA16(ah[kt], wf[kt], a);
          float biz = Lbih[32 + lc], bhz = Lbhh[32 + lc];
          #pragma unroll
          for (int i = 0; i < 4; i++) zg[i] = sigm(accI[1][i] + biz + a[i] + bhz);
        }
        {
          v8s wf[8];
          #pragma unroll
          for (int kt = 0; kt < 8; kt++)
            wf[kt] = *(const v8s*)&Lw[(HH_L + (2*2 + wv)*8 + kt)*512 + lane*8];
          f32x4 a = (f32x4){0.f,0.f,0.f,0.f};
          #pragma unroll
          for (int kt = 0; kt < 8; kt++) a = MFMA16(ah[kt], wf[kt], a);
          float bin = Lbih[64 + lc], bhn = Lbhh[64 + lc];
          #pragma unroll
          for (int i = 0; i < 4; i++){
            int r = q*4 + i;
            float ng = tanhx(accI[2][i] + bin + rg[i]*(a[i] + bhn));
            float hv = (1.f - zg[i])*ng + zg[i]*hFr[i];
            hFr[i] = hv;
            unsigned short hb = f2bf(hv);
            stxs(&A.XH[(((size_t)(1 - p)*256 + sl + j)*16 + r)*32 + lc], hb);
            __builtin_nontemporal_store(hb, &A.Hb[((size_t)(b0 + r)*127 + t)*256 + gc]);
          }
        }
      }
      // hoist: pv from Pbuf (read-only, no barrier dependency)
      unsigned short pv[4];
      #pragma unroll
      for (int i = 0; i < 4; i++)
        pv[i] = __builtin_nontemporal_load(
            &A.Pbuf[((size_t)(b0 + q*4 + i)*TN + (t+1))*256 + gc]);
      gsync(FH, j, (unsigned)(t+1), tid);
      // ---- po1h -> m1 ----
      {
        v8s ah2[8], wf[8];
        #pragma unroll
        for (int kt = 0; kt < 8; kt++)
          ah2[kt] = ldx16(A.XH + (((size_t)(1 - p)*256 + sl + kt)*16 + c16)*32 + q*8);
        #pragma unroll
        for (int kt = 0; kt < 8; kt++)
          wf[kt] = *(const v8s*)&Lw[(P1_L + wv*8 + kt)*512 + lane*8];
        f32x4 acc = (f32x4){0.f,0.f,0.f,0.f};
        #pragma unroll
        for (int kt = 0; kt < 8; kt++) acc = MFMA16(ah2[kt], wf[kt], acc);
        #pragma unroll
        for (int i = 0; i < 4; i++)
          stxs(&A.XM1[((sl + j)*16 + q*4 + i)*32 + lc],
               f2bf(fmaxf(acc[i] + bf2f(pv[i]), 0.f)));
      }
    } else {
      // ---- prologue: m1 = relu(po1_o[:, t=0]) (belief = 0) ----
      #pragma unroll
      for (int i = 0; i < 4; i++){
        int r = q*4 + i;
        unsigned short pv0 = __builtin_nontemporal_load(
            &A.Pbuf[((size_t)(b0 + r)*TN + 0)*256 + gc]);
        stxs(&A.XM1[((sl + j)*16 + r)*32 + lc], f2bf(fmaxf(bf2f(pv0), 0.f)));
      }
    }
    gsync(FM1, j, (unsigned)(t+2), tid);
    // ---- po2 -> m2 ----
    {
      v8s am[8], wf[8];
      #pragma unroll
      for (int kt = 0; kt < 8; kt++)
        am[kt] = ldx16(A.XM1 + ((sl + kt)*16 + c16)*32 + q*8);
      #pragma unroll
      for (int kt = 0; kt < 8; kt++)
        wf[kt] = *(const v8s*)&Lw[(P2_L + wv*8 + kt)*512 + lane*8];
      f32x4 acc = (f32x4){0.f,0.f,0.f,0.f};
      #pragma unroll
      for (int kt = 0; kt < 8; kt++) acc = MFMA16(am[kt], wf[kt], acc);
      #pragma unroll
      for (int i = 0; i < 4; i++)
        stxs(&A.XM2[((sl + j)*16 + q*4 + i)*32 + lc],
             f2bf(fmaxf(acc[i] + Lbp2[lc], 0.f)));
    }
    gsync(FM2, j, (unsigned)(t+2), tid);
    // ---- heads (FULL, replicated): wave0 = mu (all 128), wave1 = var ----
    {
      v8s am[8];
      #pragma unroll
      for (int kt = 0; kt < 8; kt++)
        am[kt] = ldx16(A.XM2 + ((sl + kt)*16 + c16)*32 + q*8);
      const unsigned short* wt = A.wt;
      int tb = wv ? POV_T : POM_T;
      f32x4 acc2[8];
      #pragma unroll
      for (int nt = 0; nt < 8; nt++){
        acc2[nt] = (f32x4){0.f,0.f,0.f,0.f};
        #pragma unroll
        for (int kt = 0; kt < 8; kt++)
          acc2[nt] = MFMA16(am[kt], LDB(tb + nt*8 + kt), acc2[nt]);
      }
      if (wv){
        #pragma unroll
        for (int nt = 0; nt < 8; nt++)
          #pragma unroll
          for (int i = 0; i < 4; i++)
            varF[(q*4 + i)*128 + nt*16 + c16] =
                __expf(acc2[nt][i] + Lbv[nt*16 + c16]) + 0.01f;
      }
      if (t + 1 < TN - 1)
        aF[tid] = __builtin_nontemporal_load(
            &A.actions[((size_t)(b0 + (tid >> 3))*127 + (t+1))*8 + (tid & 7)]);
      __syncthreads();
      // ---- sample (wave0 holds full mu in acc2): s block-local in sF ----
      if (!wv){
        #pragma unroll
        for (int nt = 0; nt < 8; nt++){
          #pragma unroll
          for (int i = 0; i < 4; i++){
            int r = q*4 + i, c = nt*16 + c16;
            float mq = acc2[nt][i] + Lbm[c];
            float vq = varF[r*128 + c];
            float ep2 = __builtin_nontemporal_load(
                &A.noise[((size_t)(t+1)*BN + b0 + r)*LATN + c]);
            float sv = mq + sqrtf(vq)*ep2;
            sF[r*136 + c] = f2bf(sv);
            if (nt == j)
              __builtin_nontemporal_store(sv,
                  &A.out[((size_t)(b0 + r)*TN + (t+1))*LATN + c]);
          }
        }
      }
      __syncthreads();
    }
  }
}

// ---------------------------------------------------------------------------
// Parallel post-pass: 64 rows per block (4 x 16-row subtiles) to cut
// cross-block weight re-reads 4x. prior + posterior + KL per row.
// ---------------------------------------------------------------------------
__global__ __launch_bounds__(1024, 4) void post_pass(
    const unsigned short* __restrict__ wt,
    const unsigned short* __restrict__ Pbuf,
    const unsigned short* __restrict__ Hb,
    const float* __restrict__ b_pr1, const float* __restrict__ b_pr2,
    const float* __restrict__ b_prm, const float* __restrict__ b_prv,
    const float* __restrict__ b_po2, const float* __restrict__ b_pom,
    const float* __restrict__ b_pov,
    float* __restrict__ out)
{
  __shared__ unsigned short hC[16*AB_S];
  __shared__ unsigned short X1[16*AB_S];
  __shared__ unsigned short X2[16*AB_S];
  __shared__ float mupF[16*LATN], varpF[16*LATN];
  __shared__ float muqF[16*LATN], varqF[16*LATN];

  int tid = threadIdx.x, lane = tid & 63, wv = tid >> 6;

  for (int sub = 0; sub < 4; sub++){
    int row0 = blockIdx.x * 64 + sub * 16;

    if (tid < 512){
      int r = tid >> 5, c8 = (tid & 31)*8;
      *(v8s*)&hC[r*AB_S + c8] = *(const v8s*)&Hb[(size_t)(row0 + r)*256 + c8];
    }
    __syncthreads();

    stage256(hC, wt, PR1_T, b_pr1, X1, lane, wv);
    __syncthreads();
    stage256(X1, wt, PR2_T, b_pr2, X2, lane, wv);
    __syncthreads();
    pheads(X2, wt, PRM_T, PRV_T, b_prm, b_prv, mupF, varpF, lane, wv);
    __syncthreads();

    pstage_add(hC, wt, PO1H_T, Pbuf, row0, X1, lane, wv);
    __syncthreads();
    stage256(X1, wt, PO2_T, b_po2, X2, lane, wv);
    __syncthreads();
    pheads(X2, wt, POM_T, POV_T, b_pom, b_pov, muqF, varqF, lane, wv);
    __syncthreads();

    {
      int r = wv;
      float kv = 0.f;
      #pragma unroll
      for (int ii = 0; ii < 2; ii++){
        int c = lane + ii*64;
        float mq = muqF[r*LATN + c], vq = varqF[r*LATN + c];
        float mp = mupF[r*LATN + c], vp = varpF[r*LATN + c];
        float d = mq - mp;
        kv += __logf(vp) - __logf(vq) + (vq + d*d)/vp - 1.f;
      }
      #pragma unroll
      for (int m = 1; m < 64; m <<= 1) kv += __shfl_xor(kv, m, 64);
      if (lane == 0)
        __builtin_nontemporal_store(0.5f*kv, &out[KL_OFF + (size_t)(row0 + r)]);
    }
    __syncthreads();
  }
}

// ---------------------------------------------------------------------------
extern "C" void kernel_launch(void* const* d_in, const int* in_sizes, int n_in,
                              void* d_out, int out_size, void* d_ws, size_t ws_size,
                              hipStream_t stream)
{
  (void)in_sizes; (void)n_in; (void)out_size; (void)ws_size;
  const float* vis    = (const float*)d_in[0];
  const float* acts   = (const float*)d_in[1];
  const float* noise  = (const float*)d_in[2];
  const float* w_obs1 = (const float*)d_in[3];
  const float* b_obs1 = (const float*)d_in[4];
  const float* w_obs2 = (const float*)d_in[5];
  const float* b_obs2 = (const float*)d_in[6];
  const float* w_gin  = (const float*)d_in[7];
  const float* b_gin  = (const float*)d_in[8];
  const float* w_ih   = (const float*)d_in[9];
  const float* w_hh   = (const float*)d_in[10];
  const float* b_ih   = (const float*)d_in[11];
  const float* b_hh   = (const float*)d_in[12];
  const float* w_pr1  = (const float*)d_in[13];
  const float* b_pr1  = (const float*)d_in[14];
  const float* w_pr2  = (const float*)d_in[15];
  const float* b_pr2  = (const float*)d_in[16];
  const float* w_prm  = (const float*)d_in[17];
  const float* b_prm  = (const float*)d_in[18];
  const float* w_prv  = (const float*)d_in[19];
  const float* b_prv  = (const float*)d_in[20];
  const float* w_po1  = (const float*)d_in[21];
  const float* b_po1  = (const float*)d_in[22];
  const float* w_po2  = (const float*)d_in[23];
  const float* b_po2  = (const float*)d_in[24];
  const float* w_pom  = (const float*)d_in[25];
  const float* b_pom  = (const float*)d_in[26];
  const float* w_pov  = (const float*)d_in[27];
  const float* b_pov  = (const float*)d_in[28];

  unsigned short* B1 = (unsigned short*)d_ws;                       // 65536x256 bf16
  unsigned short* WT = (unsigned short*)((char*)d_ws + B1_BYTES);   // shuffled tiles
  unsigned short* Hb  = WT + (size_t)TOT_TILES*512;                 // h_t (B*127 x 256)
  unsigned short* XG  = Hb + (size_t)BN*127*256;                    // g slices
  unsigned short* XH  = XG + 32*8*512;                              // h parity slices
  unsigned short* XM1 = XH + (size_t)2*32*8*512;
  unsigned short* XM2 = XM1 + 32*8*512;
  unsigned*       FLG = (unsigned*)(XM2 + 32*8*512);                // 4 phases x 32 x 8

  ShufArgs sa;
  const float* srcs[14] = {w_obs1, w_obs2, w_po1, w_po1, w_gin, w_ih, w_hh,
                           w_pr1, w_pr2, w_prm, w_prv, w_po2, w_pom, w_pov};
  const int strides[14] = {512,256,512,512,136,256,256,256,256,256,256,256,256,256};
  const int coloffs[14] = {0,0,256,0,0,0,0,0,0,0,0,0,0,0};
  const int ktl[14]     = {16,8,8,8,4,8,8,8,8,8,8,8,8,8};
  const int tbas[14]    = {OBS1_T,OBS2_T,PO1O_T,PO1H_T,GINS_T,IH_T,HH_T,
                           PR1_T,PR2_T,PRM_T,PRV_T,PO2_T,POM_T,POV_T};
  const int tcnt[14]    = {256,128,128,128,64,384,384,128,128,64,64,128,64,64};
  for (int i = 0; i < 14; i++){
    sa.src[i] = srcs[i]; sa.stride[i] = strides[i]; sa.coloff[i] = coloffs[i];
    sa.ktiles[i] = ktl[i]; sa.tbase[i] = tbas[i]; sa.tcnt[i] = tcnt[i];
  }
  shuffle_w<<<TOT_TILES, 64, 0, stream>>>(sa, WT);

  // obs MLP + po1_o, all in-place in B1 (rows are block-exclusive)
  big_gemm<<<1024, 256, 0, stream>>>(vis, 1, 512, WT, OBS1_T, b_obs1, 1, B1);
  big_gemm<<<1024, 256, 0, stream>>>(B1,  0, 256, WT, OBS2_T, b_obs2, 1, B1);
  big_gemm<<<1024, 256, 0, stream>>>(B1,  0, 256, WT, PO1O_T, b_po1,  0, B1);

  // zero H parity buffers + barrier flags (replayed each graph run)
  hipMemsetAsync(XH, 0, (size_t)2*32*8*512*2, stream);
  hipMemsetAsync(FLG, 0, 4*32*8*4, stream);

  RnnArgs ra;
  ra.wt = WT; ra.Pbuf = B1;
  ra.actions = acts; ra.noise = noise; ra.w_gin = w_gin;
  ra.b_gin = b_gin; ra.b_ih = b_ih; ra.b_hh = b_hh;
  ra.b_po2 = b_po2; ra.b_pom = b_pom; ra.b_pov = b_pov;
  ra.Hb = Hb; ra.XG = XG; ra.XH = XH; ra.XM1 = XM1; ra.XM2 = XM2;
  ra.flg = FLG; ra.out = (float*)d_out;
  rssm_rnn<<<256, 128, 0, stream>>>(ra);

  post_pass<<<1016, 1024, 0, stream>>>(WT, B1, Hb, b_pr1, b_pr2, b_prm, b_prv,
                                       b_po2, b_pom, b_pov, (float*)d_out);
}